// Round 2
// baseline (212.495 us; speedup 1.0000x reference)
//
#include <hip/hip_runtime.h>

#define CODEBOOK 1024
#define NGROUPS  8
#define CPG      128
#define Bn 32
#define Cn 256
#define Hn 32
#define Wn 32

#define ZQ_OFF   0
#define LOSS_OFF (Bn*Cn*Hn*Wn)      /* 8388608 */
#define IDX_OFF  (LOSS_OFF + 3)     /* 8388611 */

// ---------------------------------------------------------------- A0: proj^T
__global__ __launch_bounds__(256) void transpose_proj(const float* __restrict__ proj,
                                                      float* __restrict__ projT) {
    int k = blockIdx.x;           // 0..255
    int j = threadIdx.x;          // 0..255
    projT[(size_t)k * Cn + j] = proj[(size_t)j * Cn + k];
}

// ------------------------------------------- A1: codebook = emb @ proj^T
// Sequential-k FMA chain per output element (matches BLAS/Eigen microkernel).
__global__ __launch_bounds__(256) void codebook_kernel(const float* __restrict__ emb,
                                                       const float* __restrict__ projT,
                                                       float* __restrict__ cb) {
    __shared__ float emb8[8][Cn];
    const int t  = threadIdx.x;
    const int i0 = blockIdx.x * 8;
#pragma unroll
    for (int m = 0; m < 8; ++m) {
        int id = t + m * 256;            // 0..2047
        int ci = id >> 8, k = id & 255;
        emb8[ci][k] = emb[(size_t)(i0 + ci) * Cn + k];
    }
    __syncthreads();
    float acc[8] = {0.f,0.f,0.f,0.f,0.f,0.f,0.f,0.f};
    for (int k = 0; k < Cn; ++k) {
        float pj = projT[(size_t)k * Cn + t];
#pragma unroll
        for (int ci = 0; ci < 8; ++ci)
            acc[ci] = __builtin_fmaf(emb8[ci][k], pj, acc[ci]);
    }
#pragma unroll
    for (int ci = 0; ci < 8; ++ci)
        cb[(size_t)(i0 + ci) * Cn + t] = acc[ci];
}

// --------------------------------------------------- A2: per-code |c|^2
// Order-insensitive (sub-grid perturbations of C_i cannot flip comparisons).
__global__ __launch_bounds__(64) void norm_kernel(const float* __restrict__ cb,
                                                  float* __restrict__ norms) {
    int i = blockIdx.x, l = threadIdx.x;
    float4 v = *(const float4*)(cb + (size_t)i * Cn + l * 4);
    float s = v.x*v.x + v.y*v.y + v.z*v.z + v.w*v.w;
#pragma unroll
    for (int off = 32; off > 0; off >>= 1) s += __shfl_down(s, off);
    if (l == 0) norms[i] = s;
}

// ------------------------------------------------------------- B: main VQ
// Block = (b, 16-row h tile, group g): 64 tokens x 128 codes x K=256.
// Thread tile: 4 tokens x 8 codes, sequential-k FMA accumulation.
__global__ __launch_bounds__(256) void vq_main(const float* __restrict__ z,
                                               const float* __restrict__ cb,
                                               const float* __restrict__ norms,
                                               float* __restrict__ out,
                                               double* __restrict__ lacc) {
    __shared__ float ztile[64][64];   // [kk][tok]
    __shared__ float cbt[128][64];    // [ci][kk]
    __shared__ float zfin[64];
    __shared__ float red_d[64][16];
    __shared__ int   red_c[64][16];
    __shared__ int   bestidx[64];

    const int t   = threadIdx.x;
    const int bid = blockIdx.x;
    const int g   = bid & 7;
    const int ht  = (bid >> 3) & 1;
    const int b   = bid >> 4;
    const int h0  = ht * 16;
    const int w0  = g * 4;

    const float* zb  = z  + (size_t)b * (Cn * Hn * Wn);
    const float* cbg = cb + (size_t)g * CPG * Cn;

    const int tok0  = (t & 15) * 4;
    const int code0 = (t >> 4) * 8;

    float acc[4][8];
#pragma unroll
    for (int r = 0; r < 4; ++r)
#pragma unroll
        for (int c = 0; c < 8; ++c) acc[r][c] = 0.f;

    float zr[16];                     // numpy pairwise partials (lanes t<64)
#pragma unroll
    for (int q = 0; q < 16; ++q) zr[q] = 0.f;

    for (int kc = 0; kc < 4; ++kc) {
        const int k0 = kc * 64;
        // stage z tile: 64 k x 64 tokens (float4 along w)
#pragma unroll
        for (int m = 0; m < 4; ++m) {
            int id = t + m * 256;                 // 0..1023
            int kk = id >> 4, i = id & 15;
            float4 v = *(const float4*)(zb + (size_t)(k0 + kk) * (Hn * Wn)
                                        + (h0 + i) * Wn + w0);
            *(float4*)&ztile[kk][i * 4] = v;
        }
        // stage codebook tile: 128 codes x 64 k
#pragma unroll
        for (int m = 0; m < 8; ++m) {
            int id = t + m * 256;                 // 0..2047
            int ci = id >> 4, kq = id & 15;
            float4 v = *(const float4*)(cbg + (size_t)ci * Cn + k0 + kq * 4);
            *(float4*)&cbt[ci][kq * 4] = v;
        }
        __syncthreads();

        // |z|^2 partials: replicate numpy pairwise (8-acc stride-8, two halves).
        if (t < 64) {
#pragma clang fp contract(off)
            {
                const int base8 = (kc >> 1) * 8;
                for (int kk = 0; kk < 64; ++kk) {
                    float v  = ztile[kk][t];
                    float sq = v * v;             // rounded mul (no fma)
                    zr[base8 + (kk & 7)] += sq;   // rounded add
                }
            }
        }

        // register-tile GEMM: sequential k (chunks ascending, u ascending)
        for (int kb = 0; kb < 16; ++kb) {
            const int kk = kb * 4;
            float4 zt[4];
#pragma unroll
            for (int u = 0; u < 4; ++u)
                zt[u] = *(const float4*)&ztile[kk + u][tok0];
            float4 cf[8];
#pragma unroll
            for (int c = 0; c < 8; ++c)
                cf[c] = *(const float4*)&cbt[code0 + c][kk];
#pragma unroll
            for (int u = 0; u < 4; ++u) {
                const float zu[4] = {  // token components at k = kk+u
                    zt[u].x, zt[u].y, zt[u].z, zt[u].w };
                const float cu[8] = {
                    ((const float*)&cf[0])[u], ((const float*)&cf[1])[u],
                    ((const float*)&cf[2])[u], ((const float*)&cf[3])[u],
                    ((const float*)&cf[4])[u], ((const float*)&cf[5])[u],
                    ((const float*)&cf[6])[u], ((const float*)&cf[7])[u] };
#pragma unroll
                for (int r = 0; r < 4; ++r)
#pragma unroll
                    for (int c = 0; c < 8; ++c)
                        acc[r][c] = __builtin_fmaf(zu[r], cu[c], acc[r][c]);
            }
        }
        __syncthreads();
    }

    // finalize |z|^2 with numpy's pairwise combination
    if (t < 64) {
#pragma clang fp contract(off)
        {
            float zh0 = ((zr[0] + zr[1]) + (zr[2] + zr[3]))
                      + ((zr[4] + zr[5]) + (zr[6] + zr[7]));
            float zh1 = ((zr[8] + zr[9]) + (zr[10] + zr[11]))
                      + ((zr[12] + zr[13]) + (zr[14] + zr[15]));
            zfin[t] = zh0 + zh1;
        }
    }
    __syncthreads();

    // per-thread argmin over its 8 codes (ascending -> first-min)
    float nv[8];
    *(float4*)&nv[0] = *(const float4*)(norms + g * CPG + code0);
    *(float4*)&nv[4] = *(const float4*)(norms + g * CPG + code0 + 4);
#pragma unroll
    for (int r = 0; r < 4; ++r) {
        float zv = zfin[tok0 + r];
        float bd = __builtin_inff();
        int   bc = 0;
#pragma unroll
        for (int c = 0; c < 8; ++c) {
            float s = zv + nv[c];                 // fl(Z + C_i)
            float d = s - 2.0f * acc[r][c];       // fl(S - 2T), 2T exact
            if (d < bd) { bd = d; bc = code0 + c; }
        }
        red_d[tok0 + r][t >> 4] = bd;
        red_c[tok0 + r][t >> 4] = bc;
    }
    __syncthreads();

    // cross-thread argmin, ascending code groups -> global first-min
    if (t < 64) {
        float bd = red_d[t][0];
        int   bc = red_c[t][0];
        for (int q = 1; q < 16; ++q) {
            float d = red_d[t][q];
            if (d < bd) { bd = d; bc = red_c[t][q]; }
        }
        int gidx = g * CPG + bc;
        bestidx[t] = gidx;
        int h = h0 + (t >> 2), w = w0 + (t & 3);
        out[IDX_OFF + b * (Hn * Wn) + h * Wn + w] = (float)gidx;
    }
    __syncthreads();

    // zq write (NCHW, float4 along w) + fused loss accumulation
    float lsum = 0.f;
    const size_t zbase = (size_t)b * (Cn * Hn * Wn);
#pragma unroll
    for (int m = 0; m < 16; ++m) {
        int id = t + m * 256;                     // 0..4095
        int c = id >> 4, i = id & 15;
        size_t off = zbase + (size_t)c * (Hn * Wn) + (h0 + i) * Wn + w0;
        float4 zv = *(const float4*)(z + off);
        float q0 = cb[(size_t)bestidx[i * 4 + 0] * Cn + c];
        float q1 = cb[(size_t)bestidx[i * 4 + 1] * Cn + c];
        float q2 = cb[(size_t)bestidx[i * 4 + 2] * Cn + c];
        float q3 = cb[(size_t)bestidx[i * 4 + 3] * Cn + c];
        float4 o; o.x = q0; o.y = q1; o.z = q2; o.w = q3;
        *(float4*)(out + ZQ_OFF + off) = o;
        float d0 = q0 - zv.x, d1 = q1 - zv.y, d2 = q2 - zv.z, d3 = q3 - zv.w;
        lsum = __builtin_fmaf(d0, d0, lsum);
        lsum = __builtin_fmaf(d1, d1, lsum);
        lsum = __builtin_fmaf(d2, d2, lsum);
        lsum = __builtin_fmaf(d3, d3, lsum);
    }
    __syncthreads();
    float* rr = &red_d[0][0];                     // reuse as float[256]
    rr[t] = lsum;
    __syncthreads();
    for (int s2 = 128; s2 > 0; s2 >>= 1) {
        if (t < s2) rr[t] += rr[t + s2];
        __syncthreads();
    }
    if (t == 0) atomicAdd(lacc, (double)rr[0]);
}

// ------------------------------------------------------------ C: scalars
__global__ void finalize(const double* __restrict__ lacc, float* __restrict__ out) {
    float M    = (float)(lacc[0] / (double)(Bn * Cn * Hn * Wn));
    float comm = 0.25f * M;
    out[LOSS_OFF + 0] = comm + M;   // loss
    out[LOSS_OFF + 1] = comm;       // commitment_loss
    out[LOSS_OFF + 2] = M;          // codebook_loss
}

extern "C" void kernel_launch(void* const* d_in, const int* in_sizes, int n_in,
                              void* d_out, int out_size, void* d_ws, size_t ws_size,
                              hipStream_t stream) {
    (void)in_sizes; (void)n_in; (void)out_size; (void)ws_size;
    const float* z    = (const float*)d_in[0];
    const float* emb  = (const float*)d_in[1];
    const float* proj = (const float*)d_in[2];
    float* out = (float*)d_out;

    char*   ws    = (char*)d_ws;
    float*  projT = (float*)ws;                                  // 256 KB
    float*  cb    = (float*)(ws + 262144);                       // 1 MB
    float*  norms = (float*)(ws + 262144 + 1048576);             // 4 KB
    double* lacc  = (double*)(ws + 262144 + 1048576 + 4096);     // 8 B

    hipMemsetAsync(lacc, 0, sizeof(double), stream);
    transpose_proj <<<Cn,        256, 0, stream>>>(proj, projT);
    codebook_kernel<<<CODEBOOK/8,256, 0, stream>>>(emb, projT, cb);
    norm_kernel    <<<CODEBOOK,   64, 0, stream>>>(cb, norms);
    vq_main        <<<Bn*2*NGROUPS,256,0, stream>>>(z, cb, norms, out, lacc);
    finalize       <<<1, 1, 0, stream>>>(lacc, out);
}

// Round 3
// 175.660 us; speedup vs baseline: 1.2097x; 1.2097x over previous
//
#include <hip/hip_runtime.h>

#define CODEBOOK 1024
#define NGROUPS  8
#define CPG      128
#define Bn 32
#define Cn 256
#define Hn 32
#define Wn 32

#define ZQ_OFF   0
#define LOSS_OFF (Bn*Cn*Hn*Wn)      /* 8388608 */
#define IDX_OFF  (LOSS_OFF + 3)     /* 8388611 */

// ---------------------------------------------------------------- A0: proj^T
// (also zeroes the loss accumulator so no separate memset dispatch is needed)
__global__ __launch_bounds__(256) void transpose_proj(const float* __restrict__ proj,
                                                      float* __restrict__ projT,
                                                      double* __restrict__ lacc) {
    if (blockIdx.x == 0 && threadIdx.x == 0) lacc[0] = 0.0;
    int k = blockIdx.x;           // 0..255
    int j = threadIdx.x;          // 0..255
    projT[(size_t)k * Cn + j] = proj[(size_t)j * Cn + k];
}

// ------------------------------------------- A1: codebook = emb @ proj^T
// Sequential-k FMA chain per output element (matches BLAS/Eigen microkernel).
// DO NOT reorder: cb values feed exact-tie argmin resolution downstream.
__global__ __launch_bounds__(256) void codebook_kernel(const float* __restrict__ emb,
                                                       const float* __restrict__ projT,
                                                       float* __restrict__ cb) {
    __shared__ float emb8[8][Cn];
    const int t  = threadIdx.x;
    const int i0 = blockIdx.x * 8;
#pragma unroll
    for (int m = 0; m < 8; ++m) {
        int id = t + m * 256;            // 0..2047
        int ci = id >> 8, k = id & 255;
        emb8[ci][k] = emb[(size_t)(i0 + ci) * Cn + k];
    }
    __syncthreads();
    float acc[8] = {0.f,0.f,0.f,0.f,0.f,0.f,0.f,0.f};
    for (int k = 0; k < Cn; ++k) {
        float pj = projT[(size_t)k * Cn + t];
#pragma unroll
        for (int ci = 0; ci < 8; ++ci)
            acc[ci] = __builtin_fmaf(emb8[ci][k], pj, acc[ci]);
    }
#pragma unroll
    for (int ci = 0; ci < 8; ++ci)
        cb[(size_t)(i0 + ci) * Cn + t] = acc[ci];
}

// --------------------------------------------------- A2: per-code |c|^2
// DO NOT reorder this reduction: its exact rounding passed validation.
__global__ __launch_bounds__(64) void norm_kernel(const float* __restrict__ cb,
                                                  float* __restrict__ norms) {
    int i = blockIdx.x, l = threadIdx.x;
    float4 v = *(const float4*)(cb + (size_t)i * Cn + l * 4);
    float s = v.x*v.x + v.y*v.y + v.z*v.z + v.w*v.w;
#pragma unroll
    for (int off = 32; off > 0; off >>= 1) s += __shfl_down(s, off);
    if (l == 0) norms[i] = s;
}

// ------------------------------------------------------------- B: main VQ
// Block = (b, 16-row h tile, group g): 64 tokens x 128 codes x K=256.
// Thread tile: 4 tokens x 8 codes, sequential-k FMA accumulation (exact chain
// preserved from the validated round-2 kernel; this round only changes LDS
// physical layout (XOR swizzle) and block->XCD scheduling).
__global__ __launch_bounds__(256) void vq_main(const float* __restrict__ z,
                                               const float* __restrict__ cb,
                                               const float* __restrict__ norms,
                                               float* __restrict__ out,
                                               double* __restrict__ lacc) {
    __shared__ float ztile[64][64];   // [kk][tok]
    __shared__ float cbt[128][64];    // [ci][16B-slot swizzled: kq ^ (ci>>3)]
    __shared__ float zfin[64];
    __shared__ float red_d[64][16];
    __shared__ int   red_c[64][16];
    __shared__ int   bestidx[64];

    const int t   = threadIdx.x;
    // XCD sibling swizzle: give the 8 g-siblings of a (b,ht) pair blockIds
    // that are congruent mod 8 -> same XCD under round-robin dispatch ->
    // shared z cache lines are fetched once and stay in that XCD's L2.
    const int bid = blockIdx.x;
    const int r   = bid & 7;          // XCD id under round-robin
    const int q   = bid >> 3;         // 0..63
    const int g   = q & 7;
    const int s   = ((q >> 3) << 3) | r;   // sibling-group id 0..63
    const int ht  = s & 1;
    const int b   = s >> 1;
    const int h0  = ht * 16;
    const int w0  = g * 4;

    const float* zb  = z  + (size_t)b * (Cn * Hn * Wn);
    const float* cbg = cb + (size_t)g * CPG * Cn;

    const int tok0  = (t & 15) * 4;
    const int code0 = (t >> 4) * 8;

    float acc[4][8];
#pragma unroll
    for (int rr2 = 0; rr2 < 4; ++rr2)
#pragma unroll
        for (int c = 0; c < 8; ++c) acc[rr2][c] = 0.f;

    float zr[16];                     // numpy pairwise partials (lanes t<64)
#pragma unroll
    for (int p = 0; p < 16; ++p) zr[p] = 0.f;

    for (int kc = 0; kc < 4; ++kc) {
        const int k0 = kc * 64;
        // stage z tile: 64 k x 64 tokens (float4 along w)
#pragma unroll
        for (int m = 0; m < 4; ++m) {
            int id = t + m * 256;                 // 0..1023
            int kk = id >> 4, i = id & 15;
            float4 v = *(const float4*)(zb + (size_t)(k0 + kk) * (Hn * Wn)
                                        + (h0 + i) * Wn + w0);
            *(float4*)&ztile[kk][i * 4] = v;
        }
        // stage codebook tile: 128 codes x 64 k, XOR-swizzled 16B slots
#pragma unroll
        for (int m = 0; m < 8; ++m) {
            int id = t + m * 256;                 // 0..2047
            int ci = id >> 4, kq = id & 15;
            float4 v = *(const float4*)(cbg + (size_t)ci * Cn + k0 + kq * 4);
            ((float4*)&cbt[ci][0])[kq ^ (ci >> 3)] = v;
        }
        __syncthreads();

        // |z|^2 partials: replicate numpy pairwise (8-acc stride-8, two halves).
        if (t < 64) {
#pragma clang fp contract(off)
            {
                const int base8 = (kc >> 1) * 8;
                for (int kk = 0; kk < 64; ++kk) {
                    float v  = ztile[kk][t];
                    float sq = v * v;             // rounded mul (no fma)
                    zr[base8 + (kk & 7)] += sq;   // rounded add
                }
            }
        }

        // register-tile GEMM: sequential k (chunks ascending, u ascending)
        for (int kb = 0; kb < 16; ++kb) {
            const int kk = kb * 4;
            float4 zt[4];
#pragma unroll
            for (int u = 0; u < 4; ++u)
                zt[u] = *(const float4*)&ztile[kk + u][tok0];
            float4 cf[8];
#pragma unroll
            for (int c = 0; c < 8; ++c)
                cf[c] = ((const float4*)&cbt[code0 + c][0])[kb ^ ((code0 + c) >> 3)];
#pragma unroll
            for (int u = 0; u < 4; ++u) {
                const float zu[4] = {  // token components at k = kk+u
                    zt[u].x, zt[u].y, zt[u].z, zt[u].w };
                const float cu[8] = {
                    ((const float*)&cf[0])[u], ((const float*)&cf[1])[u],
                    ((const float*)&cf[2])[u], ((const float*)&cf[3])[u],
                    ((const float*)&cf[4])[u], ((const float*)&cf[5])[u],
                    ((const float*)&cf[6])[u], ((const float*)&cf[7])[u] };
#pragma unroll
                for (int rr3 = 0; rr3 < 4; ++rr3)
#pragma unroll
                    for (int c = 0; c < 8; ++c)
                        acc[rr3][c] = __builtin_fmaf(zu[rr3], cu[c], acc[rr3][c]);
            }
        }
        __syncthreads();
    }

    // finalize |z|^2 with numpy's pairwise combination
    if (t < 64) {
#pragma clang fp contract(off)
        {
            float zh0 = ((zr[0] + zr[1]) + (zr[2] + zr[3]))
                      + ((zr[4] + zr[5]) + (zr[6] + zr[7]));
            float zh1 = ((zr[8] + zr[9]) + (zr[10] + zr[11]))
                      + ((zr[12] + zr[13]) + (zr[14] + zr[15]));
            zfin[t] = zh0 + zh1;
        }
    }
    __syncthreads();

    // per-thread argmin over its 8 codes (ascending -> first-min)
    float nv[8];
    *(float4*)&nv[0] = *(const float4*)(norms + g * CPG + code0);
    *(float4*)&nv[4] = *(const float4*)(norms + g * CPG + code0 + 4);
#pragma unroll
    for (int rr4 = 0; rr4 < 4; ++rr4) {
        float zv = zfin[tok0 + rr4];
        float bd = __builtin_inff();
        int   bc = 0;
#pragma unroll
        for (int c = 0; c < 8; ++c) {
            float ss = zv + nv[c];                // fl(Z + C_i)
            float d  = ss - 2.0f * acc[rr4][c];   // fl(S - 2T), 2T exact
            if (d < bd) { bd = d; bc = code0 + c; }
        }
        red_d[tok0 + rr4][t >> 4] = bd;
        red_c[tok0 + rr4][t >> 4] = bc;
    }
    __syncthreads();

    // cross-thread argmin, ascending code groups -> global first-min
    if (t < 64) {
        float bd = red_d[t][0];
        int   bc = red_c[t][0];
        for (int p = 1; p < 16; ++p) {
            float d = red_d[t][p];
            if (d < bd) { bd = d; bc = red_c[t][p]; }
        }
        int gidx = g * CPG + bc;
        bestidx[t] = gidx;
        int h = h0 + (t >> 2), w = w0 + (t & 3);
        out[IDX_OFF + b * (Hn * Wn) + h * Wn + w] = (float)gidx;
    }
    __syncthreads();

    // zq write (NCHW, float4 along w) + fused loss accumulation
    float lsum = 0.f;
    const size_t zbase = (size_t)b * (Cn * Hn * Wn);
#pragma unroll
    for (int m = 0; m < 16; ++m) {
        int id = t + m * 256;                     // 0..4095
        int c = id >> 4, i = id & 15;
        size_t off = zbase + (size_t)c * (Hn * Wn) + (h0 + i) * Wn + w0;
        float4 zv = *(const float4*)(z + off);
        float q0 = cb[(size_t)bestidx[i * 4 + 0] * Cn + c];
        float q1 = cb[(size_t)bestidx[i * 4 + 1] * Cn + c];
        float q2 = cb[(size_t)bestidx[i * 4 + 2] * Cn + c];
        float q3 = cb[(size_t)bestidx[i * 4 + 3] * Cn + c];
        float4 o; o.x = q0; o.y = q1; o.z = q2; o.w = q3;
        *(float4*)(out + ZQ_OFF + off) = o;
        float d0 = q0 - zv.x, d1 = q1 - zv.y, d2 = q2 - zv.z, d3 = q3 - zv.w;
        lsum = __builtin_fmaf(d0, d0, lsum);
        lsum = __builtin_fmaf(d1, d1, lsum);
        lsum = __builtin_fmaf(d2, d2, lsum);
        lsum = __builtin_fmaf(d3, d3, lsum);
    }
    __syncthreads();
    float* rr = &red_d[0][0];                     // reuse as float[256]
    rr[t] = lsum;
    __syncthreads();
    for (int s2 = 128; s2 > 0; s2 >>= 1) {
        if (t < s2) rr[t] += rr[t + s2];
        __syncthreads();
    }
    if (t == 0) atomicAdd(lacc, (double)rr[0]);
}

// ------------------------------------------------------------ C: scalars
__global__ void finalize(const double* __restrict__ lacc, float* __restrict__ out) {
    float M    = (float)(lacc[0] / (double)(Bn * Cn * Hn * Wn));
    float comm = 0.25f * M;
    out[LOSS_OFF + 0] = comm + M;   // loss
    out[LOSS_OFF + 1] = comm;       // commitment_loss
    out[LOSS_OFF + 2] = M;          // codebook_loss
}

extern "C" void kernel_launch(void* const* d_in, const int* in_sizes, int n_in,
                              void* d_out, int out_size, void* d_ws, size_t ws_size,
                              hipStream_t stream) {
    (void)in_sizes; (void)n_in; (void)out_size; (void)ws_size;
    const float* z    = (const float*)d_in[0];
    const float* emb  = (const float*)d_in[1];
    const float* proj = (const float*)d_in[2];
    float* out = (float*)d_out;

    char*   ws    = (char*)d_ws;
    float*  projT = (float*)ws;                                  // 256 KB
    float*  cb    = (float*)(ws + 262144);                       // 1 MB
    float*  norms = (float*)(ws + 262144 + 1048576);             // 4 KB
    double* lacc  = (double*)(ws + 262144 + 1048576 + 4096);     // 8 B

    transpose_proj <<<Cn,        256, 0, stream>>>(proj, projT, lacc);
    codebook_kernel<<<CODEBOOK/8,256, 0, stream>>>(emb, projT, cb);
    norm_kernel    <<<CODEBOOK,   64, 0, stream>>>(cb, norms);
    vq_main        <<<Bn*2*NGROUPS,256,0, stream>>>(z, cb, norms, out, lacc);
    finalize       <<<1, 1, 0, stream>>>(lacc, out);
}